// Round 7
// baseline (145.072 us; speedup 1.0000x reference)
//
#include <hip/hip_runtime.h>

typedef unsigned short u16;
typedef unsigned int u32;
typedef __attribute__((ext_vector_type(8))) __bf16 bf16x8;
typedef __attribute__((ext_vector_type(4))) float f32x4;

#define DEVI __device__ __forceinline__
// exp(0.125*d - 16) == exp2(fmaf(d, C1, C2)):
#define C1 0.180336880f    // 0.125 * log2(e)
#define C2 (-23.0831200f)  // -16 * log2(e)

DEVI float bf2f(u16 u) {
    unsigned int v = ((unsigned int)u) << 16;
    return __uint_as_float(v);
}
DEVI u16 f2bf(float f) {
    unsigned int x = __float_as_uint(f);
    x += 0x7fffu + ((x >> 16) & 1u);   // RNE
    return (u16)(x >> 16);
}
DEVI u32 pk2(float lo, float hi) {     // pack 2 f32 -> bf16 pair (RNE)
    union { __bf16 b[2]; u32 u; } c;
    c.b[0] = (__bf16)lo; c.b[1] = (__bf16)hi;
    return c.u;
}
DEVI bf16x8 ldb8(const u16* p) {
    union { uint4 u; bf16x8 b; } c;
    c.u = *(const uint4*)p;
    return c.b;
}
DEVI f32x4 mfma32(bf16x8 a, bf16x8 b, f32x4 c) {
    return __builtin_amdgcn_mfma_f32_16x16x32_bf16(a, b, c, 0, 0, 0);
}
DEVI float clamp4(float v) { return fminf(fmaxf(v, -1e4f), 1e4f); }
DEVI float fexp2(float x) { return __builtin_amdgcn_exp2f(x); }  // v_exp_f32
// async global->LDS, 16B/lane, dest = wave-uniform base + lane*16
DEVI void gld16(const u16* g, u16* l) {
    __builtin_amdgcn_global_load_lds(
        (const __attribute__((address_space(1))) void*)g,
        (__attribute__((address_space(3))) void*)l, 16, 0, 0);
}

// ---------------------------------------------------------------------------
// Kernel 1: prep.
// ---------------------------------------------------------------------------
__global__ __launch_bounds__(256) void prep(
    const float* __restrict__ wq, const float* __restrict__ wkv,
    const float* __restrict__ wo, const float* __restrict__ x,
    const float* __restrict__ mkf, const float* __restrict__ mvf,
    u16* __restrict__ wqkvT, u16* __restrict__ woT, u16* __restrict__ xb,
    u16* __restrict__ qkv)
{
    const int bid = blockIdx.x, tid = threadIdx.x;
    if (bid < 256) {
        __shared__ u16 T[64][68];
        int j0, k0; const float* W; int ldw; u16* Out;
        if (bid < 192) { int jt = bid % 24, kt = bid / 24;
            j0 = jt * 64; k0 = kt * 64;
            if (j0 < 512) { W = wq + j0;          ldw = 512;  }
            else          { W = wkv + (j0 - 512); ldw = 1024; }
            Out = wqkvT;
        } else { int t = bid - 192;
            j0 = (t >> 3) * 64; k0 = (t & 7) * 64;
            W = wo + j0; ldw = 512; Out = woT;
        }
        const int lr = tid >> 4, lc = tid & 15;
        #pragma unroll
        for (int i = 0; i < 4; ++i) {
            int k = lr + i * 16;
            float4 v = *(const float4*)(W + (size_t)(k0 + k) * ldw + lc * 4);
            u16 p[4] = { f2bf(v.x), f2bf(v.y), f2bf(v.z), f2bf(v.w) };
            *(uint2*)&T[k][lc * 4] = *(uint2*)p;
        }
        __syncthreads();
        #pragma unroll
        for (int i = 0; i < 4; ++i) {
            int j = lr + i * 16;
            u16 p[4];
            #pragma unroll
            for (int c = 0; c < 4; ++c) p[c] = T[lc * 4 + c][j];
            *(uint2*)(Out + (size_t)(j0 + j) * 512 + k0 + lc * 4) = *(uint2*)p;
        }
    } else if (bid < 2304) {
        int e = (bid - 256) * 1024 + tid * 4;
        float4 v = *(const float4*)(x + e);
        u16 p[4] = { f2bf(v.x), f2bf(v.y), f2bf(v.z), f2bf(v.w) };
        *(uint2*)(xb + e) = *(uint2*)p;
    } else {
        int e = (bid - 2304) * 256 + tid;      // 0..131071
        int b = e >> 16, rem = e & 65535;
        int row2 = rem >> 10, c = rem & 1023;  // c<512: K cols, else V cols
        float v = 0.f;
        if (row2 < 3) {
            int hh = (c & 511) >> 6, d = c & 63;
            int src = hh * 192 + row2 * 64 + d;          // flat reshape!
            v = (c < 512) ? 8.0f * mkf[src] : 1.7320508f * mvf[src];
        }
        qkv[((size_t)b * 2112 + 2048 + row2) * 1536 + 512 + c] = f2bf(v);
    }
}

// ---------------------------------------------------------------------------
// Kernel 2/5: m97-style GEMM.  C(MxN) = A(MxK) @ BT(NxK)^T (+f32 bias).
// TM=128, TN=32*WNT (WNT=4 -> 128, WNT=2 -> 64).  BK=32, 256 threads,
// 2x2 wave grid, global_load_lds 16B staging (LDS row-major, unpadded —
// required by the lane-linear DMA mapping).  16(or 8) MFMA / iter / wave.
// mpad: orow = row + (row>>11)*mpad (qkv 2112-row batches).
// ---------------------------------------------------------------------------
template<int WNT, bool F32OUT>
__global__ __launch_bounds__(256) void gemm128(
    const u16* __restrict__ A, int lda,
    const u16* __restrict__ BT, int ldb,
    void* __restrict__ Cv, int ldc,
    const float* __restrict__ bias, int K, int mpad)
{
    constexpr int TN = 32 * WNT;
    __shared__ u16 As[128 * 32];
    __shared__ u16 Bs[TN * 32];

    const int tid = threadIdx.x;
    const int m0 = blockIdx.x * 128, n0 = blockIdx.y * TN;
    const int w = tid >> 6, lane = tid & 63, l15 = lane & 15, quad = lane >> 4;
    const int wr = w >> 1, wc = w & 1;

    const int srow = w * 16 + (lane >> 2), scg = (lane & 3) * 8;

    f32x4 acc[4][WNT];
    #pragma unroll
    for (int i = 0; i < 4; ++i)
        #pragma unroll
        for (int j = 0; j < WNT; ++j) acc[i][j] = (f32x4){0.f, 0.f, 0.f, 0.f};

    const u16* aG0 = A + (size_t)(m0 + srow) * lda + scg;
    const u16* aG1 = A + (size_t)(m0 + 64 + srow) * lda + scg;
    const u16* bG0 = BT + (size_t)(n0 + srow) * ldb + scg;
    const u16* bG1 = (WNT == 4) ? BT + (size_t)(n0 + 64 + srow) * ldb + scg : bG0;

    for (int k0 = 0; k0 < K; k0 += 32) {
        __syncthreads();                       // prior iter's frag reads done
        gld16(aG0, &As[w * 512]);
        gld16(aG1, &As[2048 + w * 512]);
        gld16(bG0, &Bs[w * 512]);
        if (WNT == 4) gld16(bG1, &Bs[2048 + w * 512]);
        aG0 += 32; aG1 += 32; bG0 += 32; bG1 += 32;
        __syncthreads();                       // barrier drains vmcnt -> ready

        bf16x8 af[4], bf[WNT];
        #pragma unroll
        for (int i = 0; i < 4; ++i)
            af[i] = ldb8(&As[(wr * 64 + 16 * i + l15) * 32 + quad * 8]);
        #pragma unroll
        for (int j = 0; j < WNT; ++j)
            bf[j] = ldb8(&Bs[(wc * (TN / 2) + 16 * j + l15) * 32 + quad * 8]);
        #pragma unroll
        for (int i = 0; i < 4; ++i)
            #pragma unroll
            for (int j = 0; j < WNT; ++j)
                acc[i][j] = mfma32(af[i], bf[j], acc[i][j]);
    }

    #pragma unroll
    for (int j = 0; j < WNT; ++j) {
        int col = n0 + wc * (TN / 2) + 16 * j + l15;
        float bv = bias ? bias[col] : 0.f;
        #pragma unroll
        for (int i = 0; i < 4; ++i) {
            #pragma unroll
            for (int r = 0; r < 4; ++r) {
                int row = m0 + wr * 64 + 16 * i + quad * 4 + r;
                int orow = row + ((row >> 11) * mpad);
                float vr = clamp4(acc[i][j][r] + bv);
                if (F32OUT) ((float*)Cv)[(size_t)orow * ldc + col] = vr;
                else        ((u16*)Cv)[(size_t)orow * ldc + col] = f2bf(vr);
            }
        }
    }
}

// ---------------------------------------------------------------------------
// Kernel 3: flash attention, S^T orientation, fixed-max softmax (exp2 form),
// split-K x5, l computed via ones-column MFMA (Vt rows 64..79 = 1.0).
// ---------------------------------------------------------------------------
__global__ __launch_bounds__(256, 5) void attn_kernel(
    const u16* __restrict__ qkv, u16* __restrict__ Opart,
    float* __restrict__ Lpart)
{
    __shared__ alignas(16) u16 Ks[64][72];
    __shared__ alignas(16) u16 Vt[80][72];   // rows 64..79: ones (l column)
    __shared__ alignas(16) u16 Ps[64][72];

    const int tid = threadIdx.x;
    const int bx = blockIdx.x;
    const int qt = bx / 5, s = bx - qt * 5;
    const int h = blockIdx.y, b = blockIdx.z;
    const int w = tid >> 6, lane = tid & 63, l15 = lane & 15, quad = lane >> 4;
    const size_t bq = (size_t)b * 2112;
    const int rq = qt * 64;
    const int ro = b * 2048 + qt * 64;

    // ---- ones rows for the l-column (written once, never overwritten) ----
    {
        int row = 64 + (tid >> 4), col = (tid & 15) * 4;
        uint2 ones = { 0x3F803F80u, 0x3F803F80u };
        *(uint2*)&Vt[row][col] = ones;
    }
    // ---- stage Q (raw; scale folded into exp2) via Ks ----
    {
        int row = tid >> 2, cg = (tid & 3) * 16;
        const u16* src = qkv + (bq + rq + row) * 1536 + h * 64 + cg;
        *(uint4*)&Ks[row][cg]     = *(const uint4*)src;
        *(uint4*)&Ks[row][cg + 8] = *(const uint4*)(src + 8);
    }
    __syncthreads();
    bf16x8 qf[2];
    qf[0] = ldb8(&Ks[16 * w + l15][quad * 8]);
    qf[1] = ldb8(&Ks[16 * w + l15][32 + quad * 8]);

    f32x4 O[4], O5;
    for (int t = 0; t < 4; ++t) O[t] = (f32x4){0.f, 0.f, 0.f, 0.f};
    O5 = (f32x4){0.f, 0.f, 0.f, 0.f};

    const int krow = tid >> 2, kcg = (tid & 3) * 16;
    const int vkp = (tid & 31) * 2, vdg = ((tid >> 5) & 7) * 8;

    const int kt0 = 7 * s - (s > 3 ? s - 3 : 0);
    const int kt1 = kt0 + (s < 3 ? 7 : 6);
    for (int kt = kt0; kt < kt1; ++kt) {
        __syncthreads();
        // ---- stage K tile ----
        const u16* ksrc = qkv + (bq + kt * 64 + krow) * 1536 + 512 + h * 64 + kcg;
        uint4 k0 = *(const uint4*)ksrc, k1 = *(const uint4*)(ksrc + 8);
        // ---- stage V^T tile (rows 0..63 only) ----
        const u16* vsrc = qkv + (bq + kt * 64 + vkp) * 1536 + 1024 + h * 64 + vdg;
        uint4 v0 = *(const uint4*)vsrc, v1 = *(const uint4*)(vsrc + 1536);
        *(uint4*)&Ks[krow][kcg]     = k0;
        *(uint4*)&Ks[krow][kcg + 8] = k1;
        {
            u32 a0[4] = {v0.x, v0.y, v0.z, v0.w};
            u32 a1[4] = {v1.x, v1.y, v1.z, v1.w};
            #pragma unroll
            for (int i = 0; i < 4; ++i) {
                u32 lo = __builtin_amdgcn_perm(a1[i], a0[i], 0x05040100u);
                u32 hi = __builtin_amdgcn_perm(a1[i], a0[i], 0x07060302u);
                *(u32*)&Vt[vdg + 2 * i][vkp]     = lo;
                *(u32*)&Vt[vdg + 2 * i + 1][vkp] = hi;
            }
        }
        __syncthreads();

        // ---- S^T = K @ Q^T : lane holds S[qrow=l15][key=16t+4quad+r] ----
        f32x4 d4[4];
        for (int t = 0; t < 4; ++t) d4[t] = (f32x4){0.f, 0.f, 0.f, 0.f};
        #pragma unroll
        for (int ks = 0; ks < 2; ++ks) {
            #pragma unroll
            for (int t = 0; t < 4; ++t) {
                bf16x8 kf = ldb8(&Ks[16 * t + l15][ks * 32 + quad * 8]);
                d4[t] = mfma32(kf, qf[ks], d4[t]);
            }
        }
        if (kt == 32) {   // keys 2048..2050 valid -> local key 16t+4quad+r < 3
            #pragma unroll
            for (int t = 1; t < 4; ++t)
                d4[t] = (f32x4){-1e9f, -1e9f, -1e9f, -1e9f};
            #pragma unroll
            for (int r = 0; r < 4; ++r)
                if (!(quad == 0 && r < 3)) d4[0][r] = -1e9f;
        }

        // ---- p = exp2(fmaf(d,C1,C2)); pack; b64 store (wave-private) ----
        #pragma unroll
        for (int t = 0; t < 4; ++t) {
            float p0 = fexp2(fmaf(d4[t][0], C1, C2));
            float p1 = fexp2(fmaf(d4[t][1], C1, C2));
            float p2 = fexp2(fmaf(d4[t][2], C1, C2));
            float p3 = fexp2(fmaf(d4[t][3], C1, C2));
            uint2 pv = { pk2(p0, p1), pk2(p2, p3) };
            *(uint2*)&Ps[16 * w + l15][16 * t + 4 * quad] = pv;
        }
        // ---- O += P @ [V | 1]  (same-wave LDS dep -> no barrier) ----
        #pragma unroll
        for (int ks = 0; ks < 2; ++ks) {
            bf16x8 af = ldb8(&Ps[16 * w + l15][ks * 32 + quad * 8]);
            #pragma unroll
            for (int dt = 0; dt < 4; ++dt) {
                bf16x8 vf = ldb8(&Vt[16 * dt + l15][ks * 32 + quad * 8]);
                O[dt] = mfma32(af, vf, O[dt]);
            }
            bf16x8 of = ldb8(&Vt[64 + l15][ks * 32 + quad * 8]);
            O5 = mfma32(af, of, O5);
        }
    }

    // ---- epilogue: O5[r] = l for qrow = quad*4+r (dup across l15) ----
    u16* Ob = Opart + (size_t)s * 4096 * 512;
    #pragma unroll
    for (int r = 0; r < 4; ++r) {
        int row = ro + 16 * w + quad * 4 + r;
        #pragma unroll
        for (int dt = 0; dt < 4; ++dt)
            Ob[(size_t)row * 512 + h * 64 + 16 * dt + l15] = f2bf(O[dt][r]);
        if (l15 == 0)
            Lpart[((size_t)s * 4096 + row) * 8 + h] = O5[r];
    }
}

// ---------------------------------------------------------------------------
// Kernel 4: merge 5 bf16 partial slabs -> bf16 outp.
// ---------------------------------------------------------------------------
__global__ __launch_bounds__(256) void merge_kernel(
    const u16* __restrict__ Opart, const float* __restrict__ Lpart,
    u16* __restrict__ outp)
{
    int e = (blockIdx.x * 256 + threadIdx.x) * 4;
    int row = e >> 9, h = (e & 511) >> 6;
    float ax = 0.f, ay = 0.f, az = 0.f, aw = 0.f, l = 0.f;
    #pragma unroll
    for (int s = 0; s < 5; ++s) {
        uint2 pv = *(const uint2*)(Opart + (size_t)s * 4096 * 512 + e);
        ax += bf2f((u16)(pv.x & 0xffff)); ay += bf2f((u16)(pv.x >> 16));
        az += bf2f((u16)(pv.y & 0xffff)); aw += bf2f((u16)(pv.y >> 16));
        l += Lpart[((size_t)s * 4096 + row) * 8 + h];
    }
    float rl = 1.0f / fmaxf(l, 1e-30f);
    u16 p[4] = { f2bf(clamp4(ax * rl)), f2bf(clamp4(ay * rl)),
                 f2bf(clamp4(az * rl)), f2bf(clamp4(aw * rl)) };
    *(uint2*)(outp + e) = *(uint2*)p;
}

// ---------------------------------------------------------------------------
extern "C" void kernel_launch(void* const* d_in, const int* in_sizes, int n_in,
                              void* d_out, int out_size, void* d_ws, size_t ws_size,
                              hipStream_t stream)
{
    (void)in_sizes; (void)n_in; (void)out_size; (void)ws_size;
    const float* x   = (const float*)d_in[0];
    const float* wq  = (const float*)d_in[1];
    const float* wkv = (const float*)d_in[2];
    const float* wo  = (const float*)d_in[3];
    const float* bo  = (const float*)d_in[4];
    const float* mk  = (const float*)d_in[5];
    const float* mv  = (const float*)d_in[6];
    float* out = (float*)d_out;

    u16* qkv   = (u16*)d_ws;                     // 2*2112*1536
    u16* outp  = qkv + 6488064;                  // 4096*512
    u16* woT   = outp + 2097152;                 // 512*512
    float* Lpart = (float*)(woT + 262144);       // 5*4096*8 f32
    u16* scratch = (u16*)(Lpart + 163840);
    u16* wqkvT = scratch;                        // phase 1
    u16* xb    = scratch + 786432;               // phase 1
    u16* Opart = scratch;                        // phase 2 (5*4096*512)

    prep<<<2816, 256, 0, stream>>>(wq, wkv, wo, x, mk, mv, wqkvT, woT, xb, qkv);
    gemm128<4, false><<<dim3(32, 12), 256, 0, stream>>>(
        xb, 512, wqkvT, 512, qkv, 1536, nullptr, 512, 64);
    attn_kernel<<<dim3(160, 8, 2), 256, 0, stream>>>(qkv, Opart, Lpart);
    merge_kernel<<<2048, 256, 0, stream>>>(Opart, Lpart, outp);
    gemm128<2, true><<<dim3(32, 8), 256, 0, stream>>>(
        outp, 512, woT, 512, out, 512, bo, 512, 0);
}

// Round 8
// 137.987 us; speedup vs baseline: 1.0513x; 1.0513x over previous
//
#include <hip/hip_runtime.h>

typedef unsigned short u16;
typedef unsigned int u32;
typedef __attribute__((ext_vector_type(8))) __bf16 bf16x8;
typedef __attribute__((ext_vector_type(4))) float f32x4;

#define DEVI __device__ __forceinline__
// exp(0.125*d - 16) == exp2(fmaf(d, C1, C2)):
#define C1 0.180336880f    // 0.125 * log2(e)
#define C2 (-23.0831200f)  // -16 * log2(e)

DEVI float bf2f(u16 u) {
    unsigned int v = ((unsigned int)u) << 16;
    return __uint_as_float(v);
}
DEVI u16 f2bf(float f) {
    unsigned int x = __float_as_uint(f);
    x += 0x7fffu + ((x >> 16) & 1u);   // RNE
    return (u16)(x >> 16);
}
DEVI u32 pk2(float lo, float hi) {     // pack 2 f32 -> bf16 pair (RNE)
    union { __bf16 b[2]; u32 u; } c;
    c.b[0] = (__bf16)lo; c.b[1] = (__bf16)hi;
    return c.u;
}
DEVI bf16x8 ldb8(const u16* p) {
    union { uint4 u; bf16x8 b; } c;
    c.u = *(const uint4*)p;
    return c.b;
}
DEVI f32x4 mfma32(bf16x8 a, bf16x8 b, f32x4 c) {
    return __builtin_amdgcn_mfma_f32_16x16x32_bf16(a, b, c, 0, 0, 0);
}
DEVI float clamp4(float v) { return fminf(fmaxf(v, -1e4f), 1e4f); }
DEVI float fexp2(float x) { return __builtin_amdgcn_exp2f(x); }  // v_exp_f32
// async global->LDS, 16B/lane, dest = wave-uniform base + lane*16
DEVI void gld16(const u16* g, u16* l) {
    __builtin_amdgcn_global_load_lds(
        (const __attribute__((address_space(1))) void*)g,
        (__attribute__((address_space(3))) void*)l, 16, 0, 0);
}

// ---------------------------------------------------------------------------
// Kernel 1: prep.  (unchanged from R7)
// ---------------------------------------------------------------------------
__global__ __launch_bounds__(256) void prep(
    const float* __restrict__ wq, const float* __restrict__ wkv,
    const float* __restrict__ wo, const float* __restrict__ x,
    const float* __restrict__ mkf, const float* __restrict__ mvf,
    u16* __restrict__ wqkvT, u16* __restrict__ woT, u16* __restrict__ xb,
    u16* __restrict__ qkv)
{
    const int bid = blockIdx.x, tid = threadIdx.x;
    if (bid < 256) {
        __shared__ u16 T[64][68];
        int j0, k0; const float* W; int ldw; u16* Out;
        if (bid < 192) { int jt = bid % 24, kt = bid / 24;
            j0 = jt * 64; k0 = kt * 64;
            if (j0 < 512) { W = wq + j0;          ldw = 512;  }
            else          { W = wkv + (j0 - 512); ldw = 1024; }
            Out = wqkvT;
        } else { int t = bid - 192;
            j0 = (t >> 3) * 64; k0 = (t & 7) * 64;
            W = wo + j0; ldw = 512; Out = woT;
        }
        const int lr = tid >> 4, lc = tid & 15;
        #pragma unroll
        for (int i = 0; i < 4; ++i) {
            int k = lr + i * 16;
            float4 v = *(const float4*)(W + (size_t)(k0 + k) * ldw + lc * 4);
            u16 p[4] = { f2bf(v.x), f2bf(v.y), f2bf(v.z), f2bf(v.w) };
            *(uint2*)&T[k][lc * 4] = *(uint2*)p;
        }
        __syncthreads();
        #pragma unroll
        for (int i = 0; i < 4; ++i) {
            int j = lr + i * 16;
            u16 p[4];
            #pragma unroll
            for (int c = 0; c < 4; ++c) p[c] = T[lc * 4 + c][j];
            *(uint2*)(Out + (size_t)(j0 + j) * 512 + k0 + lc * 4) = *(uint2*)p;
        }
    } else if (bid < 2304) {
        int e = (bid - 256) * 1024 + tid * 4;
        float4 v = *(const float4*)(x + e);
        u16 p[4] = { f2bf(v.x), f2bf(v.y), f2bf(v.z), f2bf(v.w) };
        *(uint2*)(xb + e) = *(uint2*)p;
    } else {
        int e = (bid - 2304) * 256 + tid;      // 0..131071
        int b = e >> 16, rem = e & 65535;
        int row2 = rem >> 10, c = rem & 1023;  // c<512: K cols, else V cols
        float v = 0.f;
        if (row2 < 3) {
            int hh = (c & 511) >> 6, d = c & 63;
            int src = hh * 192 + row2 * 64 + d;          // flat reshape!
            v = (c < 512) ? 8.0f * mkf[src] : 1.7320508f * mvf[src];
        }
        qkv[((size_t)b * 2112 + 2048 + row2) * 1536 + 512 + c] = f2bf(v);
    }
}

// ---------------------------------------------------------------------------
// Kernel 2/5: m97-style GEMM (unchanged from R7).
// ---------------------------------------------------------------------------
template<int WNT, bool F32OUT>
__global__ __launch_bounds__(256) void gemm128(
    const u16* __restrict__ A, int lda,
    const u16* __restrict__ BT, int ldb,
    void* __restrict__ Cv, int ldc,
    const float* __restrict__ bias, int K, int mpad)
{
    constexpr int TN = 32 * WNT;
    __shared__ u16 As[128 * 32];
    __shared__ u16 Bs[TN * 32];

    const int tid = threadIdx.x;
    const int m0 = blockIdx.x * 128, n0 = blockIdx.y * TN;
    const int w = tid >> 6, lane = tid & 63, l15 = lane & 15, quad = lane >> 4;
    const int wr = w >> 1, wc = w & 1;

    const int srow = w * 16 + (lane >> 2), scg = (lane & 3) * 8;

    f32x4 acc[4][WNT];
    #pragma unroll
    for (int i = 0; i < 4; ++i)
        #pragma unroll
        for (int j = 0; j < WNT; ++j) acc[i][j] = (f32x4){0.f, 0.f, 0.f, 0.f};

    const u16* aG0 = A + (size_t)(m0 + srow) * lda + scg;
    const u16* aG1 = A + (size_t)(m0 + 64 + srow) * lda + scg;
    const u16* bG0 = BT + (size_t)(n0 + srow) * ldb + scg;
    const u16* bG1 = (WNT == 4) ? BT + (size_t)(n0 + 64 + srow) * ldb + scg : bG0;

    for (int k0 = 0; k0 < K; k0 += 32) {
        __syncthreads();                       // prior iter's frag reads done
        gld16(aG0, &As[w * 512]);
        gld16(aG1, &As[2048 + w * 512]);
        gld16(bG0, &Bs[w * 512]);
        if (WNT == 4) gld16(bG1, &Bs[2048 + w * 512]);
        aG0 += 32; aG1 += 32; bG0 += 32; bG1 += 32;
        __syncthreads();                       // barrier drains vmcnt -> ready

        bf16x8 af[4], bf[WNT];
        #pragma unroll
        for (int i = 0; i < 4; ++i)
            af[i] = ldb8(&As[(wr * 64 + 16 * i + l15) * 32 + quad * 8]);
        #pragma unroll
        for (int j = 0; j < WNT; ++j)
            bf[j] = ldb8(&Bs[(wc * (TN / 2) + 16 * j + l15) * 32 + quad * 8]);
        #pragma unroll
        for (int i = 0; i < 4; ++i)
            #pragma unroll
            for (int j = 0; j < WNT; ++j)
                acc[i][j] = mfma32(af[i], bf[j], acc[i][j]);
    }

    #pragma unroll
    for (int j = 0; j < WNT; ++j) {
        int col = n0 + wc * (TN / 2) + 16 * j + l15;
        float bv = bias ? bias[col] : 0.f;
        #pragma unroll
        for (int i = 0; i < 4; ++i) {
            #pragma unroll
            for (int r = 0; r < 4; ++r) {
                int row = m0 + wr * 64 + 16 * i + quad * 4 + r;
                int orow = row + ((row >> 11) * mpad);
                float vr = clamp4(acc[i][j][r] + bv);
                if (F32OUT) ((float*)Cv)[(size_t)orow * ldc + col] = vr;
                else        ((u16*)Cv)[(size_t)orow * ldc + col] = f2bf(vr);
            }
        }
    }
}

// ---------------------------------------------------------------------------
// Kernel 3: flash attention.  128 q-rows per block: each wave holds 2 Q-frag
// sets (rows 16w.. and 64+16w..) and reuses every K/V fragment read for both
// -> LDS read traffic per unit work drops 1.8x vs R7.  S^T orientation,
// fixed-max softmax (exp2), l via ones-column MFMA, split-K x4.
// blockIdx.x = qt*4 + s; tile ranges {0-8, 9-16, 17-24, 25-32}.
// LDS: Ks 9K + Vt 11.25K + Ps 18K = 38.3 KB -> 4 blocks/CU.
// ---------------------------------------------------------------------------
__global__ __launch_bounds__(256, 4) void attn_kernel(
    const u16* __restrict__ qkv, u16* __restrict__ Opart,
    float* __restrict__ Lpart)
{
    __shared__ alignas(16) u16 Ks[64][72];
    __shared__ alignas(16) u16 Vt[80][72];    // rows 64..79: ones (l column)
    __shared__ alignas(16) u16 Ps[128][72];   // Q at start, then P (2 subtiles)

    const int tid = threadIdx.x;
    const int bx = blockIdx.x;
    const int qt = bx >> 2, s = bx & 3;
    const int h = blockIdx.y, b = blockIdx.z;
    const int w = tid >> 6, lane = tid & 63, l15 = lane & 15, quad = lane >> 4;
    const size_t bq = (size_t)b * 2112;
    const int rq = qt * 128;
    const int ro = b * 2048 + qt * 128;

    // ---- ones rows for the l-column (never overwritten) ----
    {
        int row = 64 + (tid >> 4), col = (tid & 15) * 4;
        uint2 ones = { 0x3F803F80u, 0x3F803F80u };
        *(uint2*)&Vt[row][col] = ones;
    }
    // ---- stage Q 128x64 into Ps (raw; scale folded into exp2) ----
    {
        int row = tid >> 1, cg = (tid & 1) * 32;
        const u16* src = qkv + (bq + rq + row) * 1536 + h * 64 + cg;
        *(uint4*)&Ps[row][cg]      = *(const uint4*)src;
        *(uint4*)&Ps[row][cg + 8]  = *(const uint4*)(src + 8);
        *(uint4*)&Ps[row][cg + 16] = *(const uint4*)(src + 16);
        *(uint4*)&Ps[row][cg + 24] = *(const uint4*)(src + 24);
    }
    __syncthreads();
    bf16x8 qfA[2], qfB[2];
    qfA[0] = ldb8(&Ps[16 * w + l15][quad * 8]);
    qfA[1] = ldb8(&Ps[16 * w + l15][32 + quad * 8]);
    qfB[0] = ldb8(&Ps[64 + 16 * w + l15][quad * 8]);
    qfB[1] = ldb8(&Ps[64 + 16 * w + l15][32 + quad * 8]);

    f32x4 OA[4], OB[4], O5A, O5B;
    #pragma unroll
    for (int t = 0; t < 4; ++t) {
        OA[t] = (f32x4){0.f, 0.f, 0.f, 0.f};
        OB[t] = (f32x4){0.f, 0.f, 0.f, 0.f};
    }
    O5A = (f32x4){0.f, 0.f, 0.f, 0.f};
    O5B = (f32x4){0.f, 0.f, 0.f, 0.f};

    const int krow = tid >> 2, kcg = (tid & 3) * 16;
    const int vkp = (tid & 31) * 2, vdg = ((tid >> 5) & 7) * 8;

    const int kt0 = s ? 8 * s + 1 : 0;        // {0,9,17,25}
    const int kt1 = 8 * s + 9;                // {9,17,25,33}
    for (int kt = kt0; kt < kt1; ++kt) {
        // ---- global loads early (K tile + V tile) ----
        const u16* ksrc = qkv + (bq + kt * 64 + krow) * 1536 + 512 + h * 64 + kcg;
        uint4 k0 = *(const uint4*)ksrc, k1 = *(const uint4*)(ksrc + 8);
        const u16* vsrc = qkv + (bq + kt * 64 + vkp) * 1536 + 1024 + h * 64 + vdg;
        uint4 v0 = *(const uint4*)vsrc, v1 = *(const uint4*)(vsrc + 1536);
        __syncthreads();   // prior iter's frag reads done
        *(uint4*)&Ks[krow][kcg]     = k0;
        *(uint4*)&Ks[krow][kcg + 8] = k1;
        {
            u32 a0[4] = {v0.x, v0.y, v0.z, v0.w};
            u32 a1[4] = {v1.x, v1.y, v1.z, v1.w};
            #pragma unroll
            for (int i = 0; i < 4; ++i) {
                u32 lo = __builtin_amdgcn_perm(a1[i], a0[i], 0x05040100u);
                u32 hi = __builtin_amdgcn_perm(a1[i], a0[i], 0x07060302u);
                *(u32*)&Vt[vdg + 2 * i][vkp]     = lo;
                *(u32*)&Vt[vdg + 2 * i + 1][vkp] = hi;
            }
        }
        __syncthreads();

        // ---- S^T = K @ Q^T for both subtiles; each kf read used twice ----
        f32x4 dA[4], dB[4];
        #pragma unroll
        for (int t = 0; t < 4; ++t) {
            dA[t] = (f32x4){0.f, 0.f, 0.f, 0.f};
            dB[t] = (f32x4){0.f, 0.f, 0.f, 0.f};
        }
        #pragma unroll
        for (int ks = 0; ks < 2; ++ks) {
            #pragma unroll
            for (int t = 0; t < 4; ++t) {
                bf16x8 kf = ldb8(&Ks[16 * t + l15][ks * 32 + quad * 8]);
                dA[t] = mfma32(kf, qfA[ks], dA[t]);
                dB[t] = mfma32(kf, qfB[ks], dB[t]);
            }
        }
        if (kt == 32) {   // keys 2048..2050 valid -> local key 16t+4quad+r < 3
            #pragma unroll
            for (int t = 1; t < 4; ++t) {
                dA[t] = (f32x4){-1e9f, -1e9f, -1e9f, -1e9f};
                dB[t] = (f32x4){-1e9f, -1e9f, -1e9f, -1e9f};
            }
            #pragma unroll
            for (int r = 0; r < 4; ++r)
                if (!(quad == 0 && r < 3)) { dA[0][r] = -1e9f; dB[0][r] = -1e9f; }
        }

        // ---- p = exp2(fmaf(d,C1,C2)); b64 stores (wave-private rows) ----
        #pragma unroll
        for (int t = 0; t < 4; ++t) {
            uint2 pa = { pk2(fexp2(fmaf(dA[t][0], C1, C2)),
                             fexp2(fmaf(dA[t][1], C1, C2))),
                         pk2(fexp2(fmaf(dA[t][2], C1, C2)),
                             fexp2(fmaf(dA[t][3], C1, C2))) };
            *(uint2*)&Ps[16 * w + l15][16 * t + 4 * quad] = pa;
            uint2 pb = { pk2(fexp2(fmaf(dB[t][0], C1, C2)),
                             fexp2(fmaf(dB[t][1], C1, C2))),
                         pk2(fexp2(fmaf(dB[t][2], C1, C2)),
                             fexp2(fmaf(dB[t][3], C1, C2))) };
            *(uint2*)&Ps[64 + 16 * w + l15][16 * t + 4 * quad] = pb;
        }
        // ---- O += P @ [V | 1]; each vf read used twice (no barrier) ----
        #pragma unroll
        for (int ks = 0; ks < 2; ++ks) {
            bf16x8 afA = ldb8(&Ps[16 * w + l15][ks * 32 + quad * 8]);
            bf16x8 afB = ldb8(&Ps[64 + 16 * w + l15][ks * 32 + quad * 8]);
            #pragma unroll
            for (int dt = 0; dt < 4; ++dt) {
                bf16x8 vf = ldb8(&Vt[16 * dt + l15][ks * 32 + quad * 8]);
                OA[dt] = mfma32(afA, vf, OA[dt]);
                OB[dt] = mfma32(afB, vf, OB[dt]);
            }
            bf16x8 of = ldb8(&Vt[64 + l15][ks * 32 + quad * 8]);
            O5A = mfma32(afA, of, O5A);
            O5B = mfma32(afB, of, O5B);
        }
    }

    // ---- epilogue: O5x[r] = l for that q-row (dup across l15) ----
    u16* Ob = Opart + (size_t)s * 4096 * 512;
    #pragma unroll
    for (int r = 0; r < 4; ++r) {
        int rowA = ro + 16 * w + quad * 4 + r;
        int rowB = rowA + 64;
        #pragma unroll
        for (int dt = 0; dt < 4; ++dt) {
            int col = h * 64 + 16 * dt + l15;
            Ob[(size_t)rowA * 512 + col] = f2bf(OA[dt][r]);
            Ob[(size_t)rowB * 512 + col] = f2bf(OB[dt][r]);
        }
        if (l15 == 0) {
            Lpart[((size_t)s * 4096 + rowA) * 8 + h] = O5A[r];
            Lpart[((size_t)s * 4096 + rowB) * 8 + h] = O5B[r];
        }
    }
}

// ---------------------------------------------------------------------------
// Kernel 4: merge 4 bf16 partial slabs -> bf16 outp.
// ---------------------------------------------------------------------------
__global__ __launch_bounds__(256) void merge_kernel(
    const u16* __restrict__ Opart, const float* __restrict__ Lpart,
    u16* __restrict__ outp)
{
    int e = (blockIdx.x * 256 + threadIdx.x) * 4;
    int row = e >> 9, h = (e & 511) >> 6;
    float ax = 0.f, ay = 0.f, az = 0.f, aw = 0.f, l = 0.f;
    #pragma unroll
    for (int s = 0; s < 4; ++s) {
        uint2 pv = *(const uint2*)(Opart + (size_t)s * 4096 * 512 + e);
        ax += bf2f((u16)(pv.x & 0xffff)); ay += bf2f((u16)(pv.x >> 16));
        az += bf2f((u16)(pv.y & 0xffff)); aw += bf2f((u16)(pv.y >> 16));
        l += Lpart[((size_t)s * 4096 + row) * 8 + h];
    }
    float rl = 1.0f / fmaxf(l, 1e-30f);
    u16 p[4] = { f2bf(clamp4(ax * rl)), f2bf(clamp4(ay * rl)),
                 f2bf(clamp4(az * rl)), f2bf(clamp4(aw * rl)) };
    *(uint2*)(outp + e) = *(uint2*)p;
}

// ---------------------------------------------------------------------------
extern "C" void kernel_launch(void* const* d_in, const int* in_sizes, int n_in,
                              void* d_out, int out_size, void* d_ws, size_t ws_size,
                              hipStream_t stream)
{
    (void)in_sizes; (void)n_in; (void)out_size; (void)ws_size;
    const float* x   = (const float*)d_in[0];
    const float* wq  = (const float*)d_in[1];
    const float* wkv = (const float*)d_in[2];
    const float* wo  = (const float*)d_in[3];
    const float* bo  = (const float*)d_in[4];
    const float* mk  = (const float*)d_in[5];
    const float* mv  = (const float*)d_in[6];
    float* out = (float*)d_out;

    u16* qkv   = (u16*)d_ws;                     // 2*2112*1536
    u16* outp  = qkv + 6488064;                  // 4096*512
    u16* woT   = outp + 2097152;                 // 512*512
    float* Lpart = (float*)(woT + 262144);       // 4*4096*8 f32 (<=163840 slot)
    u16* scratch = (u16*)(Lpart + 163840);
    u16* wqkvT = scratch;                        // phase 1
    u16* xb    = scratch + 786432;               // phase 1
    u16* Opart = scratch;                        // phase 2 (4*4096*512)

    prep<<<2816, 256, 0, stream>>>(wq, wkv, wo, x, mk, mv, wqkvT, woT, xb, qkv);
    gemm128<4, false><<<dim3(32, 12), 256, 0, stream>>>(
        xb, 512, wqkvT, 512, qkv, 1536, nullptr, 512, 64);
    attn_kernel<<<dim3(64, 8, 2), 256, 0, stream>>>(qkv, Opart, Lpart);
    merge_kernel<<<2048, 256, 0, stream>>>(Opart, Lpart, outp);
    gemm128<2, true><<<dim3(32, 8), 256, 0, stream>>>(
        outp, 512, woT, 512, out, 512, bo, 512, 0);
}

// Round 9
// 135.782 us; speedup vs baseline: 1.0684x; 1.0162x over previous
//
#include <hip/hip_runtime.h>

typedef unsigned short u16;
typedef unsigned int u32;
typedef __attribute__((ext_vector_type(8))) __bf16 bf16x8;
typedef __attribute__((ext_vector_type(4))) float f32x4;

#define DEVI __device__ __forceinline__
// exp(0.125*d - 16) == exp2(fmaf(d, C1, C2)):
#define C1 0.180336880f    // 0.125 * log2(e)
#define C2 (-23.0831200f)  // -16 * log2(e)

DEVI float bf2f(u16 u) {
    unsigned int v = ((unsigned int)u) << 16;
    return __uint_as_float(v);
}
DEVI u16 f2bf(float f) {
    unsigned int x = __float_as_uint(f);
    x += 0x7fffu + ((x >> 16) & 1u);   // RNE
    return (u16)(x >> 16);
}
DEVI u32 pk2(float lo, float hi) {     // pack 2 f32 -> bf16 pair (RNE)
    union { __bf16 b[2]; u32 u; } c;
    c.b[0] = (__bf16)lo; c.b[1] = (__bf16)hi;
    return c.u;
}
DEVI bf16x8 ldb8(const u16* p) {
    union { uint4 u; bf16x8 b; } c;
    c.u = *(const uint4*)p;
    return c.b;
}
DEVI f32x4 mfma32(bf16x8 a, bf16x8 b, f32x4 c) {
    return __builtin_amdgcn_mfma_f32_16x16x32_bf16(a, b, c, 0, 0, 0);
}
DEVI float clamp4(float v) { return fminf(fmaxf(v, -1e4f), 1e4f); }
DEVI float fexp2(float x) { return __builtin_amdgcn_exp2f(x); }  // v_exp_f32
// async global->LDS, 16B/lane, dest = wave-uniform base + lane*16
DEVI void gld16(const u16* g, u16* l) {
    __builtin_amdgcn_global_load_lds(
        (const __attribute__((address_space(1))) void*)g,
        (__attribute__((address_space(3))) void*)l, 16, 0, 0);
}

// ---------------------------------------------------------------------------
// Kernel 1: prep.  (unchanged from R8)
// ---------------------------------------------------------------------------
__global__ __launch_bounds__(256) void prep(
    const float* __restrict__ wq, const float* __restrict__ wkv,
    const float* __restrict__ wo, const float* __restrict__ x,
    const float* __restrict__ mkf, const float* __restrict__ mvf,
    u16* __restrict__ wqkvT, u16* __restrict__ woT, u16* __restrict__ xb,
    u16* __restrict__ qkv)
{
    const int bid = blockIdx.x, tid = threadIdx.x;
    if (bid < 256) {
        __shared__ u16 T[64][68];
        int j0, k0; const float* W; int ldw; u16* Out;
        if (bid < 192) { int jt = bid % 24, kt = bid / 24;
            j0 = jt * 64; k0 = kt * 64;
            if (j0 < 512) { W = wq + j0;          ldw = 512;  }
            else          { W = wkv + (j0 - 512); ldw = 1024; }
            Out = wqkvT;
        } else { int t = bid - 192;
            j0 = (t >> 3) * 64; k0 = (t & 7) * 64;
            W = wo + j0; ldw = 512; Out = woT;
        }
        const int lr = tid >> 4, lc = tid & 15;
        #pragma unroll
        for (int i = 0; i < 4; ++i) {
            int k = lr + i * 16;
            float4 v = *(const float4*)(W + (size_t)(k0 + k) * ldw + lc * 4);
            u16 p[4] = { f2bf(v.x), f2bf(v.y), f2bf(v.z), f2bf(v.w) };
            *(uint2*)&T[k][lc * 4] = *(uint2*)p;
        }
        __syncthreads();
        #pragma unroll
        for (int i = 0; i < 4; ++i) {
            int j = lr + i * 16;
            u16 p[4];
            #pragma unroll
            for (int c = 0; c < 4; ++c) p[c] = T[lc * 4 + c][j];
            *(uint2*)(Out + (size_t)(j0 + j) * 512 + k0 + lc * 4) = *(uint2*)p;
        }
    } else if (bid < 2304) {
        int e = (bid - 256) * 1024 + tid * 4;
        float4 v = *(const float4*)(x + e);
        u16 p[4] = { f2bf(v.x), f2bf(v.y), f2bf(v.z), f2bf(v.w) };
        *(uint2*)(xb + e) = *(uint2*)p;
    } else {
        int e = (bid - 2304) * 256 + tid;      // 0..131071
        int b = e >> 16, rem = e & 65535;
        int row2 = rem >> 10, c = rem & 1023;  // c<512: K cols, else V cols
        float v = 0.f;
        if (row2 < 3) {
            int hh = (c & 511) >> 6, d = c & 63;
            int src = hh * 192 + row2 * 64 + d;          // flat reshape!
            v = (c < 512) ? 8.0f * mkf[src] : 1.7320508f * mvf[src];
        }
        qkv[((size_t)b * 2112 + 2048 + row2) * 1536 + 512 + c] = f2bf(v);
    }
}

// ---------------------------------------------------------------------------
// Kernel 2/5: gemmK.  C(MxN) = A(MxK) @ BT(NxK)^T (+f32 bias).
// TM x TN tile, BK=64 as two 32-col sub-stages (m97 64B-row LDS geometry,
// conflict-free, gld16-compatible).  2x2 wave grid, 256 threads.
// gemm1: <128,64> grid(32,24)=768 = 3/CU.  gemm2: <64,64> grid(64,8)=512 = 2/CU.
// ---------------------------------------------------------------------------
template<int TM, int TN, bool F32OUT>
__global__ __launch_bounds__(256) void gemmK(
    const u16* __restrict__ A, int lda,
    const u16* __restrict__ BT, int ldb,
    void* __restrict__ Cv, int ldc,
    const float* __restrict__ bias, int K, int mpad)
{
    constexpr int IL = TM / 32, JL = TN / 32;
    __shared__ u16 As0[TM * 32], As1[TM * 32];
    __shared__ u16 Bs0[TN * 32], Bs1[TN * 32];

    const int tid = threadIdx.x;
    const int m0 = blockIdx.x * TM, n0 = blockIdx.y * TN;
    const int w = tid >> 6, lane = tid & 63, l15 = lane & 15, quad = lane >> 4;
    const int wr = w >> 1, wc = w & 1;
    const int sr = lane >> 2, sc = (lane & 3) * 8;   // 16-row staging op shape

    f32x4 acc[IL][JL];
    #pragma unroll
    for (int i = 0; i < IL; ++i)
        #pragma unroll
        for (int j = 0; j < JL; ++j) acc[i][j] = (f32x4){0.f, 0.f, 0.f, 0.f};

    for (int k0 = 0; k0 < K; k0 += 64) {
        __syncthreads();                       // prior iter's frag reads done
        #pragma unroll
        for (int p = 0; p < TM / 64; ++p) {    // A: wave w rows [w*TM/4 ..)
            int r0 = w * (TM / 4) + p * 16;
            const u16* g = A + (size_t)(m0 + r0 + sr) * lda + k0 + sc;
            gld16(g,      &As0[r0 * 32]);
            gld16(g + 32, &As1[r0 * 32]);
        }
        #pragma unroll
        for (int p = 0; p < TN / 64; ++p) {    // B: wave w rows [w*TN/4 ..)
            int r0 = w * (TN / 4) + p * 16;
            const u16* g = BT + (size_t)(n0 + r0 + sr) * ldb + k0 + sc;
            gld16(g,      &Bs0[r0 * 32]);
            gld16(g + 32, &Bs1[r0 * 32]);
        }
        __syncthreads();                       // barrier drains vmcnt -> ready

        #pragma unroll
        for (int ks = 0; ks < 2; ++ks) {
            const u16* Asel = ks ? As1 : As0;
            const u16* Bsel = ks ? Bs1 : Bs0;
            bf16x8 af[IL], bf[JL];
            #pragma unroll
            for (int i = 0; i < IL; ++i)
                af[i] = ldb8(&Asel[(wr * (TM / 2) + 16 * i + l15) * 32 + quad * 8]);
            #pragma unroll
            for (int j = 0; j < JL; ++j)
                bf[j] = ldb8(&Bsel[(wc * (TN / 2) + 16 * j + l15) * 32 + quad * 8]);
            #pragma unroll
            for (int i = 0; i < IL; ++i)
                #pragma unroll
                for (int j = 0; j < JL; ++j)
                    acc[i][j] = mfma32(af[i], bf[j], acc[i][j]);
        }
    }

    #pragma unroll
    for (int j = 0; j < JL; ++j) {
        int col = n0 + wc * (TN / 2) + 16 * j + l15;
        float bv = bias ? bias[col] : 0.f;
        #pragma unroll
        for (int i = 0; i < IL; ++i) {
            #pragma unroll
            for (int r = 0; r < 4; ++r) {
                int row = m0 + wr * (TM / 2) + 16 * i + quad * 4 + r;
                int orow = row + ((row >> 11) * mpad);
                float vr = clamp4(acc[i][j][r] + bv);
                if (F32OUT) ((float*)Cv)[(size_t)orow * ldc + col] = vr;
                else        ((u16*)Cv)[(size_t)orow * ldc + col] = f2bf(vr);
            }
        }
    }
}

// ---------------------------------------------------------------------------
// Kernel 3: flash attention.  256 q-rows per block: each wave holds 4 Q-frag
// sets; every K/V fragment read feeds 4 MFMA (26 b128 reads -> 72 MFMA/iter,
// vs 22->36 in R8).  S^T orientation, fixed-max softmax (exp2), l via
// ones-column MFMA, split-K x4.  blockIdx.x = qt*4 + s; ranges {0-8,9-16,
// 17-24,25-32}.  LDS: Ks 9K + Vt 11.25K + Ps 36K = 56.25 KB -> 2 blocks/CU.
// ---------------------------------------------------------------------------
__global__ __launch_bounds__(256, 2) void attn_kernel(
    const u16* __restrict__ qkv, u16* __restrict__ Opart,
    float* __restrict__ Lpart)
{
    __shared__ alignas(16) u16 Ks[64][72];
    __shared__ alignas(16) u16 Vt[80][72];    // rows 64..79: ones (l column)
    __shared__ alignas(16) u16 Ps[256][72];   // Q at start, then P (4 subtiles)

    const int tid = threadIdx.x;
    const int bx = blockIdx.x;
    const int qt = bx >> 2, s = bx & 3;
    const int h = blockIdx.y, b = blockIdx.z;
    const int w = tid >> 6, lane = tid & 63, l15 = lane & 15, quad = lane >> 4;
    const size_t bq = (size_t)b * 2112;
    const int rq = qt * 256;
    const int ro = b * 2048 + qt * 256;

    // ---- ones rows for the l-column (never overwritten) ----
    {
        int row = 64 + (tid >> 4), col = (tid & 15) * 4;
        uint2 ones = { 0x3F803F80u, 0x3F803F80u };
        *(uint2*)&Vt[row][col] = ones;
    }
    // ---- stage Q 256x64 into Ps (raw; scale folded into exp2) ----
    {
        const u16* src = qkv + (bq + rq + tid) * 1536 + h * 64;
        #pragma unroll
        for (int i = 0; i < 8; ++i)
            *(uint4*)&Ps[tid][8 * i] = *(const uint4*)(src + 8 * i);
    }
    __syncthreads();
    bf16x8 qf[4][2];
    #pragma unroll
    for (int sub = 0; sub < 4; ++sub) {
        qf[sub][0] = ldb8(&Ps[64 * sub + 16 * w + l15][quad * 8]);
        qf[sub][1] = ldb8(&Ps[64 * sub + 16 * w + l15][32 + quad * 8]);
    }

    f32x4 Od[4][4], Ol[4];
    #pragma unroll
    for (int sub = 0; sub < 4; ++sub) {
        #pragma unroll
        for (int t = 0; t < 4; ++t) Od[sub][t] = (f32x4){0.f, 0.f, 0.f, 0.f};
        Ol[sub] = (f32x4){0.f, 0.f, 0.f, 0.f};
    }

    const int krow = tid >> 2, kcg = (tid & 3) * 16;
    const int vkp = (tid & 31) * 2, vdg = ((tid >> 5) & 7) * 8;

    const int kt0 = s ? 8 * s + 1 : 0;        // {0,9,17,25}
    const int kt1 = 8 * s + 9;                // {9,17,25,33}
    for (int kt = kt0; kt < kt1; ++kt) {
        // ---- global loads early (K tile + V tile) ----
        const u16* ksrc = qkv + (bq + kt * 64 + krow) * 1536 + 512 + h * 64 + kcg;
        uint4 k0 = *(const uint4*)ksrc, k1 = *(const uint4*)(ksrc + 8);
        const u16* vsrc = qkv + (bq + kt * 64 + vkp) * 1536 + 1024 + h * 64 + vdg;
        uint4 v0 = *(const uint4*)vsrc, v1 = *(const uint4*)(vsrc + 1536);
        __syncthreads();   // prior iter's frag reads done
        *(uint4*)&Ks[krow][kcg]     = k0;
        *(uint4*)&Ks[krow][kcg + 8] = k1;
        {
            u32 a0[4] = {v0.x, v0.y, v0.z, v0.w};
            u32 a1[4] = {v1.x, v1.y, v1.z, v1.w};
            #pragma unroll
            for (int i = 0; i < 4; ++i) {
                u32 lo = __builtin_amdgcn_perm(a1[i], a0[i], 0x05040100u);
                u32 hi = __builtin_amdgcn_perm(a1[i], a0[i], 0x07060302u);
                *(u32*)&Vt[vdg + 2 * i][vkp]     = lo;
                *(u32*)&Vt[vdg + 2 * i + 1][vkp] = hi;
            }
        }
        __syncthreads();

        // ---- S^T = K @ Q^T, 4 subtiles; each kf read feeds 4 MFMA ----
        f32x4 d[4][4];
        #pragma unroll
        for (int sub = 0; sub < 4; ++sub)
            #pragma unroll
            for (int t = 0; t < 4; ++t) d[sub][t] = (f32x4){0.f, 0.f, 0.f, 0.f};
        #pragma unroll
        for (int ks = 0; ks < 2; ++ks) {
            #pragma unroll
            for (int t = 0; t < 4; ++t) {
                bf16x8 kf = ldb8(&Ks[16 * t + l15][ks * 32 + quad * 8]);
                #pragma unroll
                for (int sub = 0; sub < 4; ++sub)
                    d[sub][t] = mfma32(kf, qf[sub][ks], d[sub][t]);
            }
        }
        if (kt == 32) {   // keys 2048..2050 valid -> local key 16t+4quad+r < 3
            #pragma unroll
            for (int sub = 0; sub < 4; ++sub) {
                #pragma unroll
                for (int t = 1; t < 4; ++t)
                    d[sub][t] = (f32x4){-1e9f, -1e9f, -1e9f, -1e9f};
                #pragma unroll
                for (int r = 0; r < 4; ++r)
                    if (!(quad == 0 && r < 3)) d[sub][0][r] = -1e9f;
            }
        }

        // ---- p = exp2(fmaf(d,C1,C2)); b64 stores (wave-private rows) ----
        #pragma unroll
        for (int sub = 0; sub < 4; ++sub)
            #pragma unroll
            for (int t = 0; t < 4; ++t) {
                uint2 pv = { pk2(fexp2(fmaf(d[sub][t][0], C1, C2)),
                                 fexp2(fmaf(d[sub][t][1], C1, C2))),
                             pk2(fexp2(fmaf(d[sub][t][2], C1, C2)),
                                 fexp2(fmaf(d[sub][t][3], C1, C2))) };
                *(uint2*)&Ps[64 * sub + 16 * w + l15][16 * t + 4 * quad] = pv;
            }
        // ---- O += P @ [V | 1]; each vf read feeds 4 MFMA (no barrier) ----
        #pragma unroll
        for (int ks = 0; ks < 2; ++ks) {
            bf16x8 af[4];
            #pragma unroll
            for (int sub = 0; sub < 4; ++sub)
                af[sub] = ldb8(&Ps[64 * sub + 16 * w + l15][ks * 32 + quad * 8]);
            #pragma unroll
            for (int dt = 0; dt < 4; ++dt) {
                bf16x8 vf = ldb8(&Vt[16 * dt + l15][ks * 32 + quad * 8]);
                #pragma unroll
                for (int sub = 0; sub < 4; ++sub)
                    Od[sub][dt] = mfma32(af[sub], vf, Od[sub][dt]);
            }
            bf16x8 of = ldb8(&Vt[64 + l15][ks * 32 + quad * 8]);
            #pragma unroll
            for (int sub = 0; sub < 4; ++sub)
                Ol[sub] = mfma32(af[sub], of, Ol[sub]);
        }
    }

    // ---- epilogue ----
    u16* Ob = Opart + (size_t)s * 4096 * 512;
    #pragma unroll
    for (int sub = 0; sub < 4; ++sub) {
        #pragma unroll
        for (int r = 0; r < 4; ++r) {
            int row = ro + 64 * sub + 16 * w + quad * 4 + r;
            #pragma unroll
            for (int dt = 0; dt < 4; ++dt) {
                int col = h * 64 + 16 * dt + l15;
                Ob[(size_t)row * 512 + col] = f2bf(Od[sub][dt][r]);
            }
            if (l15 == 0)
                Lpart[((size_t)s * 4096 + row) * 8 + h] = Ol[sub][r];
        }
    }
}

// ---------------------------------------------------------------------------
// Kernel 4: merge 4 bf16 partial slabs -> bf16 outp.
// ---------------------------------------------------------------------------
__global__ __launch_bounds__(256) void merge_kernel(
    const u16* __restrict__ Opart, const float* __restrict__ Lpart,
    u16* __restrict__ outp)
{
    int e = (blockIdx.x * 256 + threadIdx.x) * 4;
    int row = e >> 9, h = (e & 511) >> 6;
    float ax = 0.f, ay = 0.f, az = 0.f, aw = 0.f, l = 0.f;
    #pragma unroll
    for (int s = 0; s < 4; ++s) {
        uint2 pv = *(const uint2*)(Opart + (size_t)s * 4096 * 512 + e);
        ax += bf2f((u16)(pv.x & 0xffff)); ay += bf2f((u16)(pv.x >> 16));
        az += bf2f((u16)(pv.y & 0xffff)); aw += bf2f((u16)(pv.y >> 16));
        l += Lpart[((size_t)s * 4096 + row) * 8 + h];
    }
    float rl = 1.0f / fmaxf(l, 1e-30f);
    u16 p[4] = { f2bf(clamp4(ax * rl)), f2bf(clamp4(ay * rl)),
                 f2bf(clamp4(az * rl)), f2bf(clamp4(aw * rl)) };
    *(uint2*)(outp + e) = *(uint2*)p;
}

// ---------------------------------------------------------------------------
extern "C" void kernel_launch(void* const* d_in, const int* in_sizes, int n_in,
                              void* d_out, int out_size, void* d_ws, size_t ws_size,
                              hipStream_t stream)
{
    (void)in_sizes; (void)n_in; (void)out_size; (void)ws_size;
    const float* x   = (const float*)d_in[0];
    const float* wq  = (const float*)d_in[1];
    const float* wkv = (const float*)d_in[2];
    const float* wo  = (const float*)d_in[3];
    const float* bo  = (const float*)d_in[4];
    const float* mk  = (const float*)d_in[5];
    const float* mv  = (const float*)d_in[6];
    float* out = (float*)d_out;

    u16* qkv   = (u16*)d_ws;                     // 2*2112*1536
    u16* outp  = qkv + 6488064;                  // 4096*512
    u16* woT   = outp + 2097152;                 // 512*512
    float* Lpart = (float*)(woT + 262144);       // 4*4096*8 f32
    u16* scratch = (u16*)(Lpart + 163840);
    u16* wqkvT = scratch;                        // phase 1
    u16* xb    = scratch + 786432;               // phase 1
    u16* Opart = scratch;                        // phase 2 (4*4096*512)

    prep<<<2816, 256, 0, stream>>>(wq, wkv, wo, x, mk, mv, wqkvT, woT, xb, qkv);
    gemmK<128, 64, false><<<dim3(32, 24), 256, 0, stream>>>(
        xb, 512, wqkvT, 512, qkv, 1536, nullptr, 512, 64);
    attn_kernel<<<dim3(32, 8, 2), 256, 0, stream>>>(qkv, Opart, Lpart);
    merge_kernel<<<2048, 256, 0, stream>>>(Opart, Lpart, outp);
    gemmK<64, 64, true><<<dim3(64, 8), 256, 0, stream>>>(
        outp, 512, woT, 512, out, 512, bo, 512, 0);
}

// Round 10
// 129.817 us; speedup vs baseline: 1.1175x; 1.0460x over previous
//
#include <hip/hip_runtime.h>

typedef unsigned short u16;
typedef unsigned int u32;
typedef __attribute__((ext_vector_type(8))) __bf16 bf16x8;
typedef __attribute__((ext_vector_type(4))) float f32x4;

#define DEVI __device__ __forceinline__
// exp(0.125*d - 16) == exp2(fmaf(d, C1, C2)):
#define C1 0.180336880f    // 0.125 * log2(e)
#define C2 (-23.0831200f)  // -16 * log2(e)

DEVI float bf2f(u16 u) {
    unsigned int v = ((unsigned int)u) << 16;
    return __uint_as_float(v);
}
DEVI u16 f2bf(float f) {
    unsigned int x = __float_as_uint(f);
    x += 0x7fffu + ((x >> 16) & 1u);   // RNE
    return (u16)(x >> 16);
}
DEVI u32 pk2(float lo, float hi) {     // pack 2 f32 -> bf16 pair (RNE)
    union { __bf16 b[2]; u32 u; } c;
    c.b[0] = (__bf16)lo; c.b[1] = (__bf16)hi;
    return c.u;
}
DEVI bf16x8 ldb8(const u16* p) {
    union { uint4 u; bf16x8 b; } c;
    c.u = *(const uint4*)p;
    return c.b;
}
DEVI f32x4 mfma32(bf16x8 a, bf16x8 b, f32x4 c) {
    return __builtin_amdgcn_mfma_f32_16x16x32_bf16(a, b, c, 0, 0, 0);
}
DEVI float clamp4(float v) { return fminf(fmaxf(v, -1e4f), 1e4f); }
DEVI float fexp2(float x) { return __builtin_amdgcn_exp2f(x); }  // v_exp_f32
// async global->LDS, 16B/lane, dest = wave-uniform base + lane*16
DEVI void gld16(const u16* g, u16* l) {
    __builtin_amdgcn_global_load_lds(
        (const __attribute__((address_space(1))) void*)g,
        (__attribute__((address_space(3))) void*)l, 16, 0, 0);
}

// ---------------------------------------------------------------------------
// Kernel 1: prep.  (unchanged)
// ---------------------------------------------------------------------------
__global__ __launch_bounds__(256) void prep(
    const float* __restrict__ wq, const float* __restrict__ wkv,
    const float* __restrict__ wo, const float* __restrict__ x,
    const float* __restrict__ mkf, const float* __restrict__ mvf,
    u16* __restrict__ wqkvT, u16* __restrict__ woT, u16* __restrict__ xb,
    u16* __restrict__ qkv)
{
    const int bid = blockIdx.x, tid = threadIdx.x;
    if (bid < 256) {
        __shared__ u16 T[64][68];
        int j0, k0; const float* W; int ldw; u16* Out;
        if (bid < 192) { int jt = bid % 24, kt = bid / 24;
            j0 = jt * 64; k0 = kt * 64;
            if (j0 < 512) { W = wq + j0;          ldw = 512;  }
            else          { W = wkv + (j0 - 512); ldw = 1024; }
            Out = wqkvT;
        } else { int t = bid - 192;
            j0 = (t >> 3) * 64; k0 = (t & 7) * 64;
            W = wo + j0; ldw = 512; Out = woT;
        }
        const int lr = tid >> 4, lc = tid & 15;
        #pragma unroll
        for (int i = 0; i < 4; ++i) {
            int k = lr + i * 16;
            float4 v = *(const float4*)(W + (size_t)(k0 + k) * ldw + lc * 4);
            u16 p[4] = { f2bf(v.x), f2bf(v.y), f2bf(v.z), f2bf(v.w) };
            *(uint2*)&T[k][lc * 4] = *(uint2*)p;
        }
        __syncthreads();
        #pragma unroll
        for (int i = 0; i < 4; ++i) {
            int j = lr + i * 16;
            u16 p[4];
            #pragma unroll
            for (int c = 0; c < 4; ++c) p[c] = T[lc * 4 + c][j];
            *(uint2*)(Out + (size_t)(j0 + j) * 512 + k0 + lc * 4) = *(uint2*)p;
        }
    } else if (bid < 2304) {
        int e = (bid - 256) * 1024 + tid * 4;
        float4 v = *(const float4*)(x + e);
        u16 p[4] = { f2bf(v.x), f2bf(v.y), f2bf(v.z), f2bf(v.w) };
        *(uint2*)(xb + e) = *(uint2*)p;
    } else {
        int e = (bid - 2304) * 256 + tid;      // 0..131071
        int b = e >> 16, rem = e & 65535;
        int row2 = rem >> 10, c = rem & 1023;  // c<512: K cols, else V cols
        float v = 0.f;
        if (row2 < 3) {
            int hh = (c & 511) >> 6, d = c & 63;
            int src = hh * 192 + row2 * 64 + d;          // flat reshape!
            v = (c < 512) ? 8.0f * mkf[src] : 1.7320508f * mvf[src];
        }
        qkv[((size_t)b * 2112 + 2048 + row2) * 1536 + 512 + c] = f2bf(v);
    }
}

// ---------------------------------------------------------------------------
// Kernel 2/5: gemmK (unchanged from R9).
// ---------------------------------------------------------------------------
template<int TM, int TN, bool F32OUT>
__global__ __launch_bounds__(256) void gemmK(
    const u16* __restrict__ A, int lda,
    const u16* __restrict__ BT, int ldb,
    void* __restrict__ Cv, int ldc,
    const float* __restrict__ bias, int K, int mpad)
{
    constexpr int IL = TM / 32, JL = TN / 32;
    __shared__ u16 As0[TM * 32], As1[TM * 32];
    __shared__ u16 Bs0[TN * 32], Bs1[TN * 32];

    const int tid = threadIdx.x;
    const int m0 = blockIdx.x * TM, n0 = blockIdx.y * TN;
    const int w = tid >> 6, lane = tid & 63, l15 = lane & 15, quad = lane >> 4;
    const int wr = w >> 1, wc = w & 1;
    const int sr = lane >> 2, sc = (lane & 3) * 8;

    f32x4 acc[IL][JL];
    #pragma unroll
    for (int i = 0; i < IL; ++i)
        #pragma unroll
        for (int j = 0; j < JL; ++j) acc[i][j] = (f32x4){0.f, 0.f, 0.f, 0.f};

    for (int k0 = 0; k0 < K; k0 += 64) {
        __syncthreads();
        #pragma unroll
        for (int p = 0; p < TM / 64; ++p) {
            int r0 = w * (TM / 4) + p * 16;
            const u16* g = A + (size_t)(m0 + r0 + sr) * lda + k0 + sc;
            gld16(g,      &As0[r0 * 32]);
            gld16(g + 32, &As1[r0 * 32]);
        }
        #pragma unroll
        for (int p = 0; p < TN / 64; ++p) {
            int r0 = w * (TN / 4) + p * 16;
            const u16* g = BT + (size_t)(n0 + r0 + sr) * ldb + k0 + sc;
            gld16(g,      &Bs0[r0 * 32]);
            gld16(g + 32, &Bs1[r0 * 32]);
        }
        __syncthreads();

        #pragma unroll
        for (int ks = 0; ks < 2; ++ks) {
            const u16* Asel = ks ? As1 : As0;
            const u16* Bsel = ks ? Bs1 : Bs0;
            bf16x8 af[IL], bf[JL];
            #pragma unroll
            for (int i = 0; i < IL; ++i)
                af[i] = ldb8(&Asel[(wr * (TM / 2) + 16 * i + l15) * 32 + quad * 8]);
            #pragma unroll
            for (int j = 0; j < JL; ++j)
                bf[j] = ldb8(&Bsel[(wc * (TN / 2) + 16 * j + l15) * 32 + quad * 8]);
            #pragma unroll
            for (int i = 0; i < IL; ++i)
                #pragma unroll
                for (int j = 0; j < JL; ++j)
                    acc[i][j] = mfma32(af[i], bf[j], acc[i][j]);
        }
    }

    #pragma unroll
    for (int j = 0; j < JL; ++j) {
        int col = n0 + wc * (TN / 2) + 16 * j + l15;
        float bv = bias ? bias[col] : 0.f;
        #pragma unroll
        for (int i = 0; i < IL; ++i) {
            #pragma unroll
            for (int r = 0; r < 4; ++r) {
                int row = m0 + wr * (TM / 2) + 16 * i + quad * 4 + r;
                int orow = row + ((row >> 11) * mpad);
                float vr = clamp4(acc[i][j][r] + bv);
                if (F32OUT) ((float*)Cv)[(size_t)orow * ldc + col] = vr;
                else        ((u16*)Cv)[(size_t)orow * ldc + col] = f2bf(vr);
            }
        }
    }
}

// ---------------------------------------------------------------------------
// Kernel 3: flash attention.  q-tile 128 (2 subtiles/wave, R8 geometry —
// 4 blocks/CU), S^T orientation, fixed-max softmax (exp2), l via MFMA
// against a REGISTER ones-fragment (no Vt ones rows, no of-reads).
// split-K x4: blockIdx.x = qt*4 + s; ranges {0-8,9-16,17-24,25-32}.
// LDS: Ks 9K + Vt 9K + Ps 18K = 36,864 B -> 4 blocks/CU (16 waves/CU).
// ---------------------------------------------------------------------------
__global__ __launch_bounds__(256, 4) void attn_kernel(
    const u16* __restrict__ qkv, u16* __restrict__ Opart,
    float* __restrict__ Lpart)
{
    __shared__ alignas(16) u16 Ks[64][72];
    __shared__ alignas(16) u16 Vt[64][72];
    __shared__ alignas(16) u16 Ps[128][72];   // Q at start, then P (2 subtiles)

    const int tid = threadIdx.x;
    const int bx = blockIdx.x;
    const int qt = bx >> 2, s = bx & 3;
    const int h = blockIdx.y, b = blockIdx.z;
    const int w = tid >> 6, lane = tid & 63, l15 = lane & 15, quad = lane >> 4;
    const size_t bq = (size_t)b * 2112;
    const int rq = qt * 128;
    const int ro = b * 2048 + qt * 128;

    // register ones-fragment for the l-column MFMA (bf16 1.0 = 0x3F80)
    union { u32 u[4]; bf16x8 b8; } onesu;
    #pragma unroll
    for (int i = 0; i < 4; ++i) onesu.u[i] = 0x3F803F80u;
    const bf16x8 onesf = onesu.b8;

    // ---- stage Q 128x64 into Ps (raw; scale folded into exp2) ----
    {
        int row = tid >> 1, cg = (tid & 1) * 32;
        const u16* src = qkv + (bq + rq + row) * 1536 + h * 64 + cg;
        *(uint4*)&Ps[row][cg]      = *(const uint4*)src;
        *(uint4*)&Ps[row][cg + 8]  = *(const uint4*)(src + 8);
        *(uint4*)&Ps[row][cg + 16] = *(const uint4*)(src + 16);
        *(uint4*)&Ps[row][cg + 24] = *(const uint4*)(src + 24);
    }
    __syncthreads();
    bf16x8 qf[2][2];
    #pragma unroll
    for (int sub = 0; sub < 2; ++sub) {
        qf[sub][0] = ldb8(&Ps[64 * sub + 16 * w + l15][quad * 8]);
        qf[sub][1] = ldb8(&Ps[64 * sub + 16 * w + l15][32 + quad * 8]);
    }

    f32x4 Od[2][4], Ol[2];
    #pragma unroll
    for (int sub = 0; sub < 2; ++sub) {
        #pragma unroll
        for (int t = 0; t < 4; ++t) Od[sub][t] = (f32x4){0.f, 0.f, 0.f, 0.f};
        Ol[sub] = (f32x4){0.f, 0.f, 0.f, 0.f};
    }

    const int krow = tid >> 2, kcg = (tid & 3) * 16;
    const int vkp = (tid & 31) * 2, vdg = ((tid >> 5) & 7) * 8;

    const int kt0 = s ? 8 * s + 1 : 0;        // {0,9,17,25}
    const int kt1 = 8 * s + 9;                // {9,17,25,33}
    for (int kt = kt0; kt < kt1; ++kt) {
        // ---- global loads early (K tile + V tile) ----
        const u16* ksrc = qkv + (bq + kt * 64 + krow) * 1536 + 512 + h * 64 + kcg;
        uint4 k0 = *(const uint4*)ksrc, k1 = *(const uint4*)(ksrc + 8);
        const u16* vsrc = qkv + (bq + kt * 64 + vkp) * 1536 + 1024 + h * 64 + vdg;
        uint4 v0 = *(const uint4*)vsrc, v1 = *(const uint4*)(vsrc + 1536);
        __syncthreads();   // prior iter's frag reads done
        *(uint4*)&Ks[krow][kcg]     = k0;
        *(uint4*)&Ks[krow][kcg + 8] = k1;
        {
            u32 a0[4] = {v0.x, v0.y, v0.z, v0.w};
            u32 a1[4] = {v1.x, v1.y, v1.z, v1.w};
            #pragma unroll
            for (int i = 0; i < 4; ++i) {
                u32 lo = __builtin_amdgcn_perm(a1[i], a0[i], 0x05040100u);
                u32 hi = __builtin_amdgcn_perm(a1[i], a0[i], 0x07060302u);
                *(u32*)&Vt[vdg + 2 * i][vkp]     = lo;
                *(u32*)&Vt[vdg + 2 * i + 1][vkp] = hi;
            }
        }
        __syncthreads();

        // ---- S^T = K @ Q^T, 2 subtiles; each kf read feeds 2 MFMA ----
        f32x4 d[2][4];
        #pragma unroll
        for (int sub = 0; sub < 2; ++sub)
            #pragma unroll
            for (int t = 0; t < 4; ++t) d[sub][t] = (f32x4){0.f, 0.f, 0.f, 0.f};
        #pragma unroll
        for (int ks = 0; ks < 2; ++ks) {
            #pragma unroll
            for (int t = 0; t < 4; ++t) {
                bf16x8 kf = ldb8(&Ks[16 * t + l15][ks * 32 + quad * 8]);
                d[0][t] = mfma32(kf, qf[0][ks], d[0][t]);
                d[1][t] = mfma32(kf, qf[1][ks], d[1][t]);
            }
        }
        if (kt == 32) {   // keys 2048..2050 valid -> local key 16t+4quad+r < 3
            #pragma unroll
            for (int sub = 0; sub < 2; ++sub) {
                #pragma unroll
                for (int t = 1; t < 4; ++t)
                    d[sub][t] = (f32x4){-1e9f, -1e9f, -1e9f, -1e9f};
                #pragma unroll
                for (int r = 0; r < 4; ++r)
                    if (!(quad == 0 && r < 3)) d[sub][0][r] = -1e9f;
            }
        }

        // ---- p = exp2(fmaf(d,C1,C2)); b64 stores (wave-private rows) ----
        #pragma unroll
        for (int sub = 0; sub < 2; ++sub)
            #pragma unroll
            for (int t = 0; t < 4; ++t) {
                uint2 pv = { pk2(fexp2(fmaf(d[sub][t][0], C1, C2)),
                                 fexp2(fmaf(d[sub][t][1], C1, C2))),
                             pk2(fexp2(fmaf(d[sub][t][2], C1, C2)),
                                 fexp2(fmaf(d[sub][t][3], C1, C2))) };
                *(uint2*)&Ps[64 * sub + 16 * w + l15][16 * t + 4 * quad] = pv;
            }
        // ---- O += P @ V; l += P @ 1 (register fragment, no LDS read) ----
        #pragma unroll
        for (int ks = 0; ks < 2; ++ks) {
            bf16x8 af0 = ldb8(&Ps[16 * w + l15][ks * 32 + quad * 8]);
            bf16x8 af1 = ldb8(&Ps[64 + 16 * w + l15][ks * 32 + quad * 8]);
            #pragma unroll
            for (int dt = 0; dt < 4; ++dt) {
                bf16x8 vf = ldb8(&Vt[16 * dt + l15][ks * 32 + quad * 8]);
                Od[0][dt] = mfma32(af0, vf, Od[0][dt]);
                Od[1][dt] = mfma32(af1, vf, Od[1][dt]);
            }
            Ol[0] = mfma32(af0, onesf, Ol[0]);
            Ol[1] = mfma32(af1, onesf, Ol[1]);
        }
    }

    // ---- epilogue ----
    u16* Ob = Opart + (size_t)s * 4096 * 512;
    #pragma unroll
    for (int sub = 0; sub < 2; ++sub) {
        #pragma unroll
        for (int r = 0; r < 4; ++r) {
            int row = ro + 64 * sub + 16 * w + quad * 4 + r;
            #pragma unroll
            for (int dt = 0; dt < 4; ++dt) {
                int col = h * 64 + 16 * dt + l15;
                Ob[(size_t)row * 512 + col] = f2bf(Od[sub][dt][r]);
            }
            if (l15 == 0)
                Lpart[((size_t)s * 4096 + row) * 8 + h] = Ol[sub][r];
        }
    }
}

// ---------------------------------------------------------------------------
// Kernel 4: merge 4 bf16 partial slabs -> bf16 outp.
// ---------------------------------------------------------------------------
__global__ __launch_bounds__(256) void merge_kernel(
    const u16* __restrict__ Opart, const float* __restrict__ Lpart,
    u16* __restrict__ outp)
{
    int e = (blockIdx.x * 256 + threadIdx.x) * 4;
    int row = e >> 9, h = (e & 511) >> 6;
    float ax = 0.f, ay = 0.f, az = 0.f, aw = 0.f, l = 0.f;
    #pragma unroll
    for (int s = 0; s < 4; ++s) {
        uint2 pv = *(const uint2*)(Opart + (size_t)s * 4096 * 512 + e);
        ax += bf2f((u16)(pv.x & 0xffff)); ay += bf2f((u16)(pv.x >> 16));
        az += bf2f((u16)(pv.y & 0xffff)); aw += bf2f((u16)(pv.y >> 16));
        l += Lpart[((size_t)s * 4096 + row) * 8 + h];
    }
    float rl = 1.0f / fmaxf(l, 1e-30f);
    u16 p[4] = { f2bf(clamp4(ax * rl)), f2bf(clamp4(ay * rl)),
                 f2bf(clamp4(az * rl)), f2bf(clamp4(aw * rl)) };
    *(uint2*)(outp + e) = *(uint2*)p;
}

// ---------------------------------------------------------------------------
extern "C" void kernel_launch(void* const* d_in, const int* in_sizes, int n_in,
                              void* d_out, int out_size, void* d_ws, size_t ws_size,
                              hipStream_t stream)
{
    (void)in_sizes; (void)n_in; (void)out_size; (void)ws_size;
    const float* x   = (const float*)d_in[0];
    const float* wq  = (const float*)d_in[1];
    const float* wkv = (const float*)d_in[2];
    const float* wo  = (const float*)d_in[3];
    const float* bo  = (const float*)d_in[4];
    const float* mk  = (const float*)d_in[5];
    const float* mv  = (const float*)d_in[6];
    float* out = (float*)d_out;

    u16* qkv   = (u16*)d_ws;                     // 2*2112*1536
    u16* outp  = qkv + 6488064;                  // 4096*512
    u16* woT   = outp + 2097152;                 // 512*512
    float* Lpart = (float*)(woT + 262144);       // 4*4096*8 f32
    u16* scratch = (u16*)(Lpart + 163840);
    u16* wqkvT = scratch;                        // phase 1
    u16* xb    = scratch + 786432;               // phase 1
    u16* Opart = scratch;                        // phase 2 (4*4096*512)

    prep<<<2816, 256, 0, stream>>>(wq, wkv, wo, x, mk, mv, wqkvT, woT, xb, qkv);
    gemmK<128, 64, false><<<dim3(32, 24), 256, 0, stream>>>(
        xb, 512, wqkvT, 512, qkv, 1536, nullptr, 512, 64);
    attn_kernel<<<dim3(64, 8, 2), 256, 0, stream>>>(qkv, Opart, Lpart);
    merge_kernel<<<2048, 256, 0, stream>>>(Opart, Lpart, outp);
    gemmK<64, 64, true><<<dim3(64, 8), 256, 0, stream>>>(
        outp, 512, woT, 512, out, 512, bo, 512, 0);
}